// Round 10
// baseline (489.441 us; speedup 1.0000x reference)
//
#include <hip/hip_runtime.h>

// GraphSAGE 2-layer, fp32. N=100000, F_IN=64, H=128, E=1.6M.
// Round 9 (resubmit; previous attempt hit an infra failure, not a kernel
// failure): fuse gather+dense per layer. R8 showed gather is latency/fabric
// bound (VALU cut 39->28% with zero time change), so cut BYTES+ROUND-TRIPS:
//  - gather writes mean as bf16 RNE into XOR-swizzled LDS (no global mean)
//  - dense A-side = single bf16 (mean from LDS, root from xb/hb global),
//    B-side keeps fp32-split weights -> 2 MFMA per frag (was 3)
//  - layer1 emits only hb (bf16); fp32 h buffer deleted
// CSR build (atomic-free deterministic scatter) unchanged from round 8.

#define EPB 16384          // edges per scatter block
#define MAXNB 1024         // max dst buckets (N<=131072)

typedef __attribute__((ext_vector_type(8))) short bf16x8;  // MFMA A/B frag
typedef __attribute__((ext_vector_type(4))) float f32x4;   // MFMA C/D frag

__device__ inline unsigned short f2bf_rne(float f) {
    unsigned u = __float_as_uint(f);
    return (unsigned short)((u + 0x7FFFu + ((u >> 16) & 1u)) >> 16);
}

// ---------------- fp32 -> bf16 (RNE) bulk convert ----------------
__global__ __launch_bounds__(256) void cvt_bf16_kernel(
    const float* __restrict__ in, unsigned short* __restrict__ out, int n)
{
    int i = (blockIdx.x * 256 + threadIdx.x) * 4;
    if (i >= n) return;
    float4 v = *reinterpret_cast<const float4*>(&in[i]);
    ushort4 o;
    o.x = f2bf_rne(v.x); o.y = f2bf_rne(v.y);
    o.z = f2bf_rne(v.z); o.w = f2bf_rne(v.w);
    *reinterpret_cast<ushort4*>(&out[i]) = o;
}

// ---------------- step 1: per-block bucket histogram ----------------
__global__ __launch_bounds__(256) void count_blocks_kernel(
    const int* __restrict__ ei, int* __restrict__ blockCounts, // [NBLK][NB]
    int E, int NB)
{
    __shared__ int hist[MAXNB];
    for (int i = threadIdx.x; i < NB; i += 256) hist[i] = 0;
    __syncthreads();
    int e0 = blockIdx.x * EPB;
    int e1 = min(e0 + EPB, E);
    for (int e = e0 + threadIdx.x; e < e1; e += 256)
        atomicAdd(&hist[ei[E + e] >> 7], 1);
    __syncthreads();
    for (int i = threadIdx.x; i < NB; i += 256)
        blockCounts[blockIdx.x * NB + i] = hist[i];
}

// ---------------- step 2: deterministic 2-level scan ----------------
__global__ __launch_bounds__(1024) void scan_buckets_kernel(
    const int* __restrict__ blockCounts,   // [NBLK][NB]
    int* __restrict__ blockBase,           // [NBLK][NB]
    int* __restrict__ bucketBase,          // [NB+1]
    int NB, int NBLK)
{
    __shared__ int tot[1024];
    int t = threadIdx.x;
    int run = 0;
    if (t < NB) {
        for (int k = 0; k < NBLK; ++k) {
            int c = blockCounts[k * NB + t];
            blockBase[k * NB + t] = run;   // prefix within bucket
            run += c;
        }
    }
    tot[t] = run;
    __syncthreads();
    for (int o = 1; o < 1024; o <<= 1) {
        int a = (t >= o) ? tot[t - o] : 0;
        __syncthreads();
        tot[t] += a;
        __syncthreads();
    }
    if (t < NB) {
        int base = tot[t] - run;           // exclusive prefix
        bucketBase[t] = base;
        for (int k = 0; k < NBLK; ++k) blockBase[k * NB + t] += base;
    }
    if (t == 0) bucketBase[NB] = tot[1023];   // == E
}

// ---------------- step 3: write pairs into block-owned runs ----------------
__global__ __launch_bounds__(256) void write_pairs_kernel(
    const int* __restrict__ ei, const int* __restrict__ blockBase,
    unsigned* __restrict__ pairs, int E, int NB)
{
    __shared__ int cur[MAXNB];
    for (int i = threadIdx.x; i < NB; i += 256)
        cur[i] = blockBase[blockIdx.x * NB + i];
    __syncthreads();
    int e0 = blockIdx.x * EPB;
    int e1 = min(e0 + EPB, E);
    for (int e = e0 + threadIdx.x; e < e1; e += 256) {
        int s = ei[e];
        int d = ei[E + e];
        int p = atomicAdd(&cur[d >> 7], 1);      // LDS atomic, ~21-deep
        pairs[p] = ((unsigned)(d & 127) << 25) | (unsigned)s;
    }
}

// ---------------- step 4: per-bucket finalize: rowptr + sorted ssrc --------
__global__ __launch_bounds__(256) void bucket_finalize_kernel(
    const unsigned* __restrict__ pairs, const int* __restrict__ bucketBase,
    int* __restrict__ rowptr, int* __restrict__ ssrc, int N)
{
    __shared__ int hist[128];
    __shared__ int scn[128];
    __shared__ int cur[128];
    int t = threadIdx.x;
    int b = blockIdx.x;
    int segS = bucketBase[b], segE = bucketBase[b + 1];
    if (t < 128) hist[t] = 0;
    __syncthreads();
    for (int i = segS + t; i < segE; i += 256)
        atomicAdd(&hist[pairs[i] >> 25], 1);
    __syncthreads();
    if (t < 128) scn[t] = hist[t];
    __syncthreads();
    for (int o = 1; o < 128; o <<= 1) {
        int a = 0;
        if (t < 128 && t >= o) a = scn[t - o];
        __syncthreads();
        if (t < 128) scn[t] += a;
        __syncthreads();
    }
    if (t < 128) {
        int start = segS + scn[t] - hist[t];     // exclusive prefix
        cur[t] = start;
        int node = b * 128 + t;
        if (node < N) rowptr[node] = start;
    }
    if (b == 0 && t == 0) rowptr[N] = bucketBase[gridDim.x];
    __syncthreads();
    for (int i = segS + t; i < segE; i += 256) {
        unsigned p = pairs[i];
        int pos = atomicAdd(&cur[p >> 25], 1);
        ssrc[pos] = (int)(p & 0x1FFFFFFu);
    }
}

// ---------------- weight prep: split + fragment-order ----------------
// Wcat[k][j] = (k<F ? Wl[j][k] : Wr[j][k-F]); w0 = bf16 trunc, w1 = residual.
__global__ __launch_bounds__(256) void prep_w_kernel(
    const float* __restrict__ Wl, const float* __restrict__ Wr, int F,
    short* __restrict__ w0f, short* __restrict__ w1f, int nfrag)
{
    int t = blockIdx.x * 256 + threadIdx.x;   // one thread per (frag, lane)
    if (t >= nfrag * 64) return;
    int lane = t & 63, fr = t >> 6;
    int j  = fr & 7, ks = fr >> 3;
    int col = j * 16 + (lane & 15);
    int k0  = ks * 32 + (lane >> 4) * 8;
    #pragma unroll
    for (int e = 0; e < 8; ++e) {
        int k = k0 + e;
        float w = (k < F) ? Wl[col * F + k] : Wr[col * F + (k - F)];
        unsigned u = __float_as_uint(w);
        unsigned h = u & 0xFFFF0000u;
        float r = w - __uint_as_float(h);
        w0f[t * 8 + e] = (short)(u >> 16);
        w1f[t * 8 + e] = (short)(__float_as_uint(r) >> 16);
    }
}

// ---------------- fused layer: gather -> LDS mean (bf16) -> MFMA ----------
// Block = 128 rows, 4 waves. Phase 1: wave wv gathers local rows
// [wv*32, wv*32+32) into XOR-swizzled LDS (byte ^= (row&7)<<4). Phase 2:
// out[row][128] = meanLDS @ (w0+w1)[mean half] + root @ (w0+w1)[root half] + bl.
// LAST=false: relu + write bf16 hb only. LAST=true: write fp32 out.
template<int F, bool LAST>
__global__ __launch_bounds__(256, 4) void fused_layer_kernel(
    const int* __restrict__ rowptr, const int* __restrict__ ssrc,
    const unsigned short* __restrict__ feat,   // [N][F] bf16: gather src + root
    const short* __restrict__ w0f, const short* __restrict__ w1f,
    const float* __restrict__ bl,              // [128]
    float* __restrict__ outf,                  // [N][128] (LAST)
    unsigned short* __restrict__ outb,         // [N][128] bf16 (!LAST)
    int N)
{
    constexpr int NS = (2 * F) / 32;          // k-steps
    constexpr int C  = F / 4;                 // lanes per gathered row
    constexpr int G  = 64 / C;                // edges in flight per step
    constexpr int RB = F * 2;                 // LDS row bytes
    constexpr int SH = (F == 128) ? 8 : 7;    // log2(global row bytes)
    __shared__ char lds[128 * RB];

    const int tid  = threadIdx.x;
    const int lane = tid & 63;
    const int wv   = tid >> 6;
    const int rowBase = blockIdx.x * 128;

    // ---------- phase 1: gather 32 rows per wave ----------
    {
        const int chunk = lane & (C - 1);
        const int grp   = lane / C;
        const unsigned cb = (unsigned)chunk * 8;
        const char* fbase = (const char*)feat;
        for (int i = 0; i < 32; ++i) {
            int lr = wv * 32 + i;
            int n  = rowBase + lr;
            if (n >= N) break;                 // wave-uniform
            int rp = rowptr[n], re = rowptr[n + 1];
            float a0 = 0.f, a1 = 0.f, a2 = 0.f, a3 = 0.f;
            int e = rp + grp;
            while (e + 7 * G < re) {
                int s[8];
                #pragma unroll
                for (int k = 0; k < 8; ++k) s[k] = ssrc[e + k * G];
                #pragma unroll
                for (int k = 0; k < 8; ++k) {
                    unsigned off = ((unsigned)s[k] << SH) + cb;
                    uint2 p = *reinterpret_cast<const uint2*>(fbase + off);
                    a0 += __uint_as_float(p.x << 16);
                    a1 += __uint_as_float(p.x & 0xFFFF0000u);
                    a2 += __uint_as_float(p.y << 16);
                    a3 += __uint_as_float(p.y & 0xFFFF0000u);
                }
                e += 8 * G;
            }
            while (e < re) {
                unsigned off = ((unsigned)ssrc[e] << SH) + cb;
                uint2 p = *reinterpret_cast<const uint2*>(fbase + off);
                a0 += __uint_as_float(p.x << 16);
                a1 += __uint_as_float(p.x & 0xFFFF0000u);
                a2 += __uint_as_float(p.y << 16);
                a3 += __uint_as_float(p.y & 0xFFFF0000u);
                e += G;
            }
            #pragma unroll
            for (int o = C; o < 64; o <<= 1) {
                a0 += __shfl_xor(a0, o);
                a1 += __shfl_xor(a1, o);
                a2 += __shfl_xor(a2, o);
                a3 += __shfl_xor(a3, o);
            }
            if (lane < C) {
                float inv = 1.0f / (float)max(re - rp, 1);
                unsigned lo = (unsigned)f2bf_rne(a0 * inv)
                            | ((unsigned)f2bf_rne(a1 * inv) << 16);
                unsigned hi = (unsigned)f2bf_rne(a2 * inv)
                            | ((unsigned)f2bf_rne(a3 * inv) << 16);
                unsigned byte = (unsigned)lr * RB
                              + (cb ^ (((unsigned)lr & 7u) << 4));
                *reinterpret_cast<uint2*>(lds + byte) = make_uint2(lo, hi);
            }
        }
    }
    __syncthreads();

    // ---------- phase 2: MFMA ----------
    const int r16 = lane & 15;
    const int kg  = lane >> 4;
    const int lrow0 = wv * 32 + r16;
    const int lrow1 = wv * 32 + 16 + r16;
    const int grow0 = min(rowBase + lrow0, N - 1);
    const int grow1 = min(rowBase + lrow1, N - 1);

    f32x4 acc[2][8];
    #pragma unroll
    for (int rt = 0; rt < 2; ++rt)
        #pragma unroll
        for (int j = 0; j < 8; ++j)
            acc[rt][j] = (f32x4){0.f, 0.f, 0.f, 0.f};

    #pragma unroll
    for (int ks = 0; ks < NS; ++ks) {
        bf16x8 a[2];
        if (ks < NS / 2) {           // mean half: swizzled LDS
            unsigned kb = (unsigned)(ks * 64 + kg * 16);
            a[0] = *reinterpret_cast<const bf16x8*>(
                lds + (unsigned)lrow0 * RB + (kb ^ (((unsigned)lrow0 & 7u) << 4)));
            a[1] = *reinterpret_cast<const bf16x8*>(
                lds + (unsigned)lrow1 * RB + (kb ^ (((unsigned)lrow1 & 7u) << 4)));
        } else {                     // root half: bf16 global (64B-line friendly)
            int ko = (ks - NS / 2) * 32 + kg * 8;
            a[0] = *reinterpret_cast<const bf16x8*>(&feat[(size_t)grow0 * F + ko]);
            a[1] = *reinterpret_cast<const bf16x8*>(&feat[(size_t)grow1 * F + ko]);
        }
        #pragma unroll
        for (int j = 0; j < 8; ++j) {
            const size_t fb = (((size_t)(ks * 8 + j)) * 64 + lane) * 8;
            const bf16x8 b0 = *reinterpret_cast<const bf16x8*>(&w0f[fb]);
            const bf16x8 b1 = *reinterpret_cast<const bf16x8*>(&w1f[fb]);
            #pragma unroll
            for (int rt = 0; rt < 2; ++rt) {
                acc[rt][j] = __builtin_amdgcn_mfma_f32_16x16x32_bf16(
                    a[rt], b0, acc[rt][j], 0, 0, 0);
                acc[rt][j] = __builtin_amdgcn_mfma_f32_16x16x32_bf16(
                    a[rt], b1, acc[rt][j], 0, 0, 0);
            }
        }
    }

    // ---------- epilogue: C/D layout col=lane&15, row=(lane>>4)*4+i ----------
    #pragma unroll
    for (int j = 0; j < 8; ++j) {
        const int col = j * 16 + r16;
        const float b = bl[col];
        #pragma unroll
        for (int rt = 0; rt < 2; ++rt) {
            const int rb = rowBase + wv * 32 + rt * 16 + kg * 4;
            #pragma unroll
            for (int i = 0; i < 4; ++i) {
                int row = rb + i;
                if (row < N) {
                    float v = acc[rt][j][i] + b;
                    if (!LAST) {
                        v = fmaxf(v, 0.f);
                        outb[(size_t)row * 128 + col] = f2bf_rne(v);
                    } else {
                        outf[(size_t)row * 128 + col] = v;
                    }
                }
            }
        }
    }
}

extern "C" void kernel_launch(void* const* d_in, const int* in_sizes, int n_in,
                              void* d_out, int out_size, void* d_ws, size_t ws_size,
                              hipStream_t stream) {
    const float* x   = (const float*)d_in[0];
    const int*   ei  = (const int*)d_in[1];
    const float* Wl1 = (const float*)d_in[2];
    const float* bl1 = (const float*)d_in[3];
    const float* Wr1 = (const float*)d_in[4];
    const float* Wl2 = (const float*)d_in[5];
    const float* bl2 = (const float*)d_in[6];
    const float* Wr2 = (const float*)d_in[7];
    float* out = (float*)d_out;

    const int N    = in_sizes[0] / 64;     // 100000
    const int E    = in_sizes[1] / 2;      // 1600000
    const int NB   = (N + 127) / 128;      // dst buckets (782)
    const int NBLK = (E + EPB - 1) / EPB;  // scatter blocks (98)

    // ws layout (~52 MB): bf16 feats | weight frags | ints | pairs
    unsigned short* xb = (unsigned short*)d_ws;        // [N*64]
    unsigned short* hb = xb + (size_t)N * 64;          // [N*128]
    short* w0f1 = (short*)(hb + (size_t)N * 128);      // 32 frags * 512
    short* w1f1 = w0f1 + 32 * 512;
    short* w0f2 = w1f1 + 32 * 512;                     // 64 frags * 512
    short* w1f2 = w0f2 + 64 * 512;
    int* ssrc        = (int*)(w1f2 + 64 * 512);        // [E]
    int* rowptr      = ssrc + E;                       // [N+1]
    int* bucketBase  = rowptr + (N + 1);               // [NB+1]
    int* blockCounts = bucketBase + (NB + 1);          // [NBLK*NB]
    int* blockBase   = blockCounts + NB * NBLK;        // [NBLK*NB]
    unsigned* pairs  = (unsigned*)(blockBase + NB * NBLK);  // [E]

    // bf16 copy of x (gather + root source for layer 1)
    cvt_bf16_kernel<<<(N * 64 / 4 + 255) / 256, 256, 0, stream>>>(x, xb, N * 64);

    // atomic-free CSR build
    count_blocks_kernel<<<NBLK, 256, 0, stream>>>(ei, blockCounts, E, NB);
    scan_buckets_kernel<<<1, 1024, 0, stream>>>(blockCounts, blockBase, bucketBase, NB, NBLK);
    write_pairs_kernel<<<NBLK, 256, 0, stream>>>(ei, blockBase, pairs, E, NB);
    bucket_finalize_kernel<<<NB, 256, 0, stream>>>(pairs, bucketBase, rowptr, ssrc, N);

    // weight prep (fragment-ordered split-bf16)
    prep_w_kernel<<<(32 * 64 + 255) / 256, 256, 0, stream>>>(Wl1, Wr1, 64, w0f1, w1f1, 32);
    prep_w_kernel<<<(64 * 64 + 255) / 256, 256, 0, stream>>>(Wl2, Wr2, 128, w0f2, w1f2, 64);

    const int dgrid = (N + 127) / 128;   // 782

    // layer 1: gather(xb) + dense -> hb (bf16, relu'd)
    fused_layer_kernel<64, false><<<dgrid, 256, 0, stream>>>(
        rowptr, ssrc, xb, w0f1, w1f1, bl1, nullptr, hb, N);

    // layer 2: gather(hb) + dense -> out (fp32)
    fused_layer_kernel<128, true><<<dgrid, 256, 0, stream>>>(
        rowptr, ssrc, hb, w0f2, w1f2, bl2, out, nullptr, N);
}